// Round 6
// baseline (92.718 us; speedup 1.0000x reference)
//
#include <hip/hip_runtime.h>
#include <hip/hip_bf16.h>
#include <math.h>

#define BB 8
#define SS 512
#define EE 128
#define HH 16
#define DKK 8

#define FMA4(ACC, S, W) do { (ACC).x += (S)*(W).x; (ACC).y += (S)*(W).y; \
                             (ACC).z += (S)*(W).z; (ACC).w += (S)*(W).w; } while(0)

// ---------------------------------------------------------------------------
// Kernel 1: QKV GEMM + bias + theta + quantum head. No LDS, no SMEM streams.
// grid (256, 3): blockIdx.x = 16-row tile of x, blockIdx.y = matrix (q/k/v).
// block 256 = 4 waves; per-lane tile 2 rows x 4 cols (cg = t&31, rg = t>>5).
// x rows: global float4, 32 lanes share the address -> L1 broadcast.
// W columns: perfectly coalesced global float4 (L2-resident, 64KB).
// Quantum head: prefix cosine products; even/odd lane pair swaps one
// 4-product via shfl_xor(1). Output layout (B, H, S, 8).
// ---------------------------------------------------------------------------
__global__ __launch_bounds__(256) void k_qkvq(
    const float* __restrict__ x,
    const float* __restrict__ Wq, const float* __restrict__ bq,
    const float* __restrict__ Wk, const float* __restrict__ bk,
    const float* __restrict__ Wv, const float* __restrict__ bv,
    const float* __restrict__ theta,
    float* __restrict__ qh, float* __restrict__ kh, float* __restrict__ vh)
{
    const int t = threadIdx.x;
    const int m = blockIdx.y;
    const int row0 = blockIdx.x * 16;

    const int cg   = t & 31;
    const int col0 = cg * 4;
    const int rg   = t >> 5;          // 0..7
    const int r0   = rg * 2;

    const float* __restrict__ W  = (m == 0) ? Wq : (m == 1) ? Wk : Wv;
    const float* __restrict__ bb = (m == 0) ? bq : (m == 1) ? bk : bv;
    float* __restrict__ outp     = (m == 0) ? qh : (m == 1) ? kh : vh;

    const float4* xr = (const float4*)(x + (size_t)(row0 + r0) * 128);

    float4 acc0 = *(const float4*)&bb[col0];
    float4 acc1 = acc0;

    #pragma unroll 4
    for (int k4 = 0; k4 < 32; ++k4) {
        const float4 xa = xr[k4];
        const float4 xb = xr[32 + k4];
        const float4 w0 = *(const float4*)&W[(k4 * 4 + 0) * 128 + col0];
        const float4 w1 = *(const float4*)&W[(k4 * 4 + 1) * 128 + col0];
        const float4 w2 = *(const float4*)&W[(k4 * 4 + 2) * 128 + col0];
        const float4 w3 = *(const float4*)&W[(k4 * 4 + 3) * 128 + col0];
        FMA4(acc0, xa.x, w0); FMA4(acc0, xa.y, w1);
        FMA4(acc0, xa.z, w2); FMA4(acc0, xa.w, w3);
        FMA4(acc1, xb.x, w0); FMA4(acc1, xb.y, w1);
        FMA4(acc1, xb.z, w2); FMA4(acc1, xb.w, w3);
    }

    const float4 th = *(const float4*)&theta[col0];
    const int h    = cg >> 1;
    const int half = cg & 1;          // 0: wires 0-3, 1: wires 4-7

    float4 accs[2] = {acc0, acc1};
    #pragma unroll
    for (int r = 0; r < 2; ++r) {
        float4 c;
        c.x = __cosf(accs[r].x + th.x);
        c.y = __cosf(accs[r].y + th.y);
        c.z = __cosf(accs[r].z + th.z);
        c.w = __cosf(accs[r].w + th.w);
        const float p0 = c.x;
        const float p1 = p0 * c.y;
        const float p2 = p1 * c.z;
        const float p3 = p2 * c.w;
        const float recv = __shfl_xor(p3, 1);
        float4 o;
        if (half == 0) {
            const float s123 = c.y * c.z * c.w;
            o.x = s123 * recv;   // wire 0: c1..c7
            o.y = p1;            // wire 1: c0c1
            o.z = p2;            // wire 2
            o.w = p3;            // wire 3
        } else {
            o.x = recv * p0;     // wire 4: (c0..c3)c4
            o.y = recv * p1;
            o.z = recv * p2;
            o.w = recv * p3;
        }
        const int g  = row0 + r0 + r;
        const int b_ = g >> 9;
        const int s  = g & 511;
        *(float4*)&outp[(((size_t)b_ * HH + h) * SS + s) * DKK + half * 4] = o;
    }
}

// ---------------------------------------------------------------------------
// Kernel 2: attention. grid 1024: bh = bid&127 (128%8==0 -> all q-chunks of
// a bh land on the SAME XCD -> K/V L2-local), qc = bid>>7 (8 chunks of 64).
// block 256 = 4 waves; wave wv covers j-range [wv*128,+128) for the block's
// 64 q rows; lane owns exactly 1 q row. K/V rows are read as wave-uniform
// VECTOR global loads (wv not readfirstlane'd, so no SMEM scalarization):
// one 64B L1/L2 broadcast serves 64 (q,j) pairs. No K/V staging, tiny LDS
// only for the 4-way j-partial combine. Single-pass softmax (|s|<=sqrt(8)).
// hid written head-major (B,H,S,8), fully coalesced.
// ---------------------------------------------------------------------------
__global__ __launch_bounds__(256) void k_attn(
    const float* __restrict__ qh, const float* __restrict__ kh,
    const float* __restrict__ vh, float* __restrict__ hid)
{
    __shared__ float part[4][64][12];

    const int t  = threadIdx.x;
    const int L  = t & 63;
    const int wv = t >> 6;            // deliberately NOT readfirstlane
    const int bh = blockIdx.x & 127;
    const int q0 = (blockIdx.x >> 7) * 64;

    // this lane's q row
    const float4* qg = (const float4*)qh + ((size_t)bh * 512 + q0 + L) * 2;
    const float4 qa = qg[0];
    const float4 qb = qg[1];

    const float4* kbase = (const float4*)kh + ((size_t)bh * 512 + wv * 128) * 2;
    const float4* vbase = (const float4*)vh + ((size_t)bh * 512 + wv * 128) * 2;

    float4 accA = make_float4(0.f, 0.f, 0.f, 0.f);
    float4 accB = make_float4(0.f, 0.f, 0.f, 0.f);
    float  den  = 0.f;
    const float scale = 0.35355339059327373f;  // 1/sqrt(8)

    #pragma unroll 4
    for (int j = 0; j < 128; ++j) {
        const float4 k0 = kbase[2 * j];
        const float4 k1 = kbase[2 * j + 1];
        const float4 v0 = vbase[2 * j];
        const float4 v1 = vbase[2 * j + 1];
        const float s = qa.x*k0.x + qa.y*k0.y + qa.z*k0.z + qa.w*k0.w
                      + qb.x*k1.x + qb.y*k1.y + qb.z*k1.z + qb.w*k1.w;
        const float e = __expf(s * scale);
        den += e;
        FMA4(accA, e, v0);
        FMA4(accB, e, v1);
    }

    float* p = &part[wv][L][0];
    ((float4*)p)[0] = accA;
    ((float4*)p)[1] = accB;
    p[8] = den;
    __syncthreads();

    if (t < 64) {
        float4 rA = make_float4(0.f, 0.f, 0.f, 0.f);
        float4 rB = make_float4(0.f, 0.f, 0.f, 0.f);
        float  rd = 0.f;
        #pragma unroll
        for (int wq = 0; wq < 4; ++wq) {
            const float* pp = &part[wq][t][0];
            const float4 a = ((const float4*)pp)[0];
            const float4 b = ((const float4*)pp)[1];
            rA.x += a.x; rA.y += a.y; rA.z += a.z; rA.w += a.w;
            rB.x += b.x; rB.y += b.y; rB.z += b.z; rB.w += b.w;
            rd   += pp[8];
        }
        const float inv = 1.0f / rd;
        rA.x *= inv; rA.y *= inv; rA.z *= inv; rA.w *= inv;
        rB.x *= inv; rB.y *= inv; rB.z *= inv; rB.w *= inv;
        float4* o = (float4*)hid + ((size_t)bh * 512 + q0 + t) * 2;
        o[0] = rA;
        o[1] = rB;
    }
}

// ---------------------------------------------------------------------------
// Kernel 3: output projection. hid is head-major (B,H,S,8); gather a 8x128
// row-major tile into LDS (transpose), then GEMM with Wo + bo.
// grid 512 x 256: 8 output rows per block (2 blocks/CU).
// ---------------------------------------------------------------------------
__global__ __launch_bounds__(256) void k_out(
    const float* __restrict__ hid, const float* __restrict__ Wo,
    const float* __restrict__ bo, float* __restrict__ out)
{
    __shared__ float hs[8][128];
    const int t = threadIdx.x;
    const int row0 = blockIdx.x * 8;

    // gather: unit u = (row, head), 2 threads per unit (one float4 each)
    {
        const int u    = t >> 1;        // 0..127
        const int half = t & 1;
        const int row  = u >> 4;        // 0..7
        const int h    = u & 15;
        const int g    = row0 + row;
        const int b_   = g >> 9;
        const int s    = g & 511;
        const float4 v = ((const float4*)hid)[(((size_t)b_ * HH + h) * SS + s) * 2 + half];
        *(float4*)&hs[row][h * 8 + half * 4] = v;
    }
    __syncthreads();

    const int cg   = t & 31;
    const int col0 = cg * 4;
    const int rr   = t >> 5;           // 0..7: one row per lane-group

    float4 acc = *(const float4*)&bo[col0];

    #pragma unroll 4
    for (int k4 = 0; k4 < 32; ++k4) {
        const float4 xa = ((const float4*)hs[rr])[k4];
        const float4 w0 = *(const float4*)&Wo[(k4 * 4 + 0) * 128 + col0];
        const float4 w1 = *(const float4*)&Wo[(k4 * 4 + 1) * 128 + col0];
        const float4 w2 = *(const float4*)&Wo[(k4 * 4 + 2) * 128 + col0];
        const float4 w3 = *(const float4*)&Wo[(k4 * 4 + 3) * 128 + col0];
        FMA4(acc, xa.x, w0); FMA4(acc, xa.y, w1);
        FMA4(acc, xa.z, w2); FMA4(acc, xa.w, w3);
    }

    *(float4*)&out[(size_t)(row0 + rr) * 128 + col0] = acc;
}

// ---------------------------------------------------------------------------
extern "C" void kernel_launch(void* const* d_in, const int* in_sizes, int n_in,
                              void* d_out, int out_size, void* d_ws, size_t ws_size,
                              hipStream_t stream)
{
    const float* x     = (const float*)d_in[0];
    const float* Wq    = (const float*)d_in[1];
    const float* bq    = (const float*)d_in[2];
    const float* Wk    = (const float*)d_in[3];
    const float* bk    = (const float*)d_in[4];
    const float* Wv    = (const float*)d_in[5];
    const float* bv    = (const float*)d_in[6];
    const float* Wo    = (const float*)d_in[7];
    const float* bo    = (const float*)d_in[8];
    const float* theta = (const float*)d_in[9];
    float* out = (float*)d_out;

    float* ws  = (float*)d_ws;
    float* qh  = ws;                   // B*H*S*8 = 524288 floats each
    float* kh  = ws + 524288;
    float* vh  = ws + 1048576;
    float* hid = ws + 1572864;         // head-major (B,H,S,8)

    k_qkvq<<<dim3(256, 3), 256, 0, stream>>>(x, Wq, bq, Wk, bk, Wv, bv,
                                             theta, qh, kh, vh);
    k_attn<<<1024, 256, 0, stream>>>(qh, kh, vh, hid);
    k_out <<<512, 256, 0, stream>>>(hid, Wo, bo, out);
}

// Round 8
// 61.208 us; speedup vs baseline: 1.5148x; 1.5148x over previous
//
#include <hip/hip_runtime.h>
#include <hip/hip_bf16.h>
#include <math.h>

#define BB 8
#define SS 512
#define EE 128
#define HH 16
#define DKK 8

#define FMA4(ACC, S, W) do { (ACC).x += (S)*(W).x; (ACC).y += (S)*(W).y; \
                             (ACC).z += (S)*(W).z; (ACC).w += (S)*(W).w; } while(0)
#define DOT4(A, B) ((A).x*(B).x + (A).y*(B).y + (A).z*(B).z + (A).w*(B).w)

// ---------------------------------------------------------------------------
// Kernel 1: QKV GEMM + bias + theta + quantum head. No LDS.
// grid (256, 3): blockIdx.x = 16-row tile of x, blockIdx.y = matrix (q/k/v).
// block 256 = 4 waves; per-lane tile 2 rows x 4 cols (cg = t&31, rg = t>>5).
// x rows: global float4, 32 lanes share the address -> L1 broadcast.
// W columns: perfectly coalesced global float4 (L2-resident, 64KB).
// Quantum head: prefix cosine products; even/odd lane pair swaps one
// 4-product via shfl_xor(1). Output layout (B, H, S, 8).
// ---------------------------------------------------------------------------
__global__ __launch_bounds__(256, 4) void k_qkvq(
    const float* __restrict__ x,
    const float* __restrict__ Wq, const float* __restrict__ bq,
    const float* __restrict__ Wk, const float* __restrict__ bk,
    const float* __restrict__ Wv, const float* __restrict__ bv,
    const float* __restrict__ theta,
    float* __restrict__ qh, float* __restrict__ kh, float* __restrict__ vh)
{
    const int t = threadIdx.x;
    const int m = blockIdx.y;
    const int row0 = blockIdx.x * 16;

    const int cg   = t & 31;
    const int col0 = cg * 4;
    const int rg   = t >> 5;          // 0..7
    const int r0   = rg * 2;

    const float* __restrict__ W  = (m == 0) ? Wq : (m == 1) ? Wk : Wv;
    const float* __restrict__ bb = (m == 0) ? bq : (m == 1) ? bk : bv;
    float* __restrict__ outp     = (m == 0) ? qh : (m == 1) ? kh : vh;

    const float4* xr = (const float4*)(x + (size_t)(row0 + r0) * 128);

    float4 acc0 = *(const float4*)&bb[col0];
    float4 acc1 = acc0;

    #pragma unroll 4
    for (int k4 = 0; k4 < 32; ++k4) {
        const float4 xa = xr[k4];
        const float4 xb = xr[32 + k4];
        const float4 w0 = *(const float4*)&W[(k4 * 4 + 0) * 128 + col0];
        const float4 w1 = *(const float4*)&W[(k4 * 4 + 1) * 128 + col0];
        const float4 w2 = *(const float4*)&W[(k4 * 4 + 2) * 128 + col0];
        const float4 w3 = *(const float4*)&W[(k4 * 4 + 3) * 128 + col0];
        FMA4(acc0, xa.x, w0); FMA4(acc0, xa.y, w1);
        FMA4(acc0, xa.z, w2); FMA4(acc0, xa.w, w3);
        FMA4(acc1, xb.x, w0); FMA4(acc1, xb.y, w1);
        FMA4(acc1, xb.z, w2); FMA4(acc1, xb.w, w3);
    }

    const float4 th = *(const float4*)&theta[col0];
    const int h    = cg >> 1;
    const int half = cg & 1;          // 0: wires 0-3, 1: wires 4-7

    float4 accs[2] = {acc0, acc1};
    #pragma unroll
    for (int r = 0; r < 2; ++r) {
        float4 c;
        c.x = __cosf(accs[r].x + th.x);
        c.y = __cosf(accs[r].y + th.y);
        c.z = __cosf(accs[r].z + th.z);
        c.w = __cosf(accs[r].w + th.w);
        const float p0 = c.x;
        const float p1 = p0 * c.y;
        const float p2 = p1 * c.z;
        const float p3 = p2 * c.w;
        const float recv = __shfl_xor(p3, 1);
        float4 o;
        if (half == 0) {
            const float s123 = c.y * c.z * c.w;
            o.x = s123 * recv;   // wire 0: c1..c7
            o.y = p1;            // wire 1: c0c1
            o.z = p2;            // wire 2
            o.w = p3;            // wire 3
        } else {
            o.x = recv * p0;     // wire 4: (c0..c3)c4
            o.y = recv * p1;
            o.z = recv * p2;
            o.w = recv * p3;
        }
        const int g  = row0 + r0 + r;
        const int b_ = g >> 9;
        const int s  = g & 511;
        *(float4*)&outp[(((size_t)b_ * HH + h) * SS + s) * DKK + half * 4] = o;
    }
}

// ---------------------------------------------------------------------------
// Kernel 2: attention. grid 512: bh = bid&127 (4 q-chunk blocks of a bh on
// the SAME XCD since 128 % 8 == 0 -> K/V L2-local), q-chunk = (bid>>7)*128
// with bid>>7 in 0..3 (512 blocks total -> all 512 q rows exactly once).
// block 256 = 4 waves, 32KB LDS. Full K+V staged in LDS; wave wv =
// j-quarter [wv*128,+128); lane owns 2 q rows (L, L+64). Broadcast
// ds_read_b128 (no conflict). Single-pass softmax (|s/sqrt(8)| <= sqrt(8)).
// After the j-loop the K/V stage is dead: partials are written into the
// SAME LDS (union), combined 4-way, normalized, written head-major.
// ---------------------------------------------------------------------------
__global__ __launch_bounds__(256, 4) void k_attn(
    const float* __restrict__ qh, const float* __restrict__ kh,
    const float* __restrict__ vh, float* __restrict__ hid)
{
    __shared__ float4 smem[2048];     // 32KB: K/V stage, then partial buffer
    float4* kk = smem;                // [1024] = 512 rows x 2 float4
    float4* vv = smem + 1024;

    const int t  = threadIdx.x;
    const int L  = t & 63;
    const int wv = t >> 6;
    const int bh = blockIdx.x & 127;
    const int q0 = (blockIdx.x >> 7) * 128;   // 0,128,256,384

    // stage K/V (2048 float4; 8 per thread, coalesced)
    {
        const float4* kg = (const float4*)kh + (size_t)bh * 1024;
        const float4* vg = (const float4*)vh + (size_t)bh * 1024;
        #pragma unroll
        for (int i = 0; i < 4; ++i) kk[t + 256 * i] = kg[t + 256 * i];
        #pragma unroll
        for (int i = 0; i < 4; ++i) vv[t + 256 * i] = vg[t + 256 * i];
    }

    // this lane's 2 q rows: q0 + L, q0 + L + 64
    const float4* qg = (const float4*)qh + ((size_t)bh * 512 + q0) * 2;
    const float4 qa0 = qg[L * 2];
    const float4 qb0 = qg[L * 2 + 1];
    const float4 qa1 = qg[(L + 64) * 2];
    const float4 qb1 = qg[(L + 64) * 2 + 1];
    __syncthreads();

    float4 aA0 = make_float4(0.f,0.f,0.f,0.f), aB0 = aA0;
    float4 aA1 = aA0, aB1 = aA0;
    float d0 = 0.f, d1 = 0.f;
    const float scale = 0.35355339059327373f;   // 1/sqrt(8)

    const float4* kbase = kk + wv * 256;        // this wave's 128 j rows
    const float4* vbase = vv + wv * 256;

    #pragma unroll 4
    for (int j = 0; j < 128; ++j) {
        const float4 k0 = kbase[2 * j];
        const float4 k1 = kbase[2 * j + 1];
        const float4 v0 = vbase[2 * j];
        const float4 v1 = vbase[2 * j + 1];
        const float s0 = DOT4(qa0, k0) + DOT4(qb0, k1);
        const float s1 = DOT4(qa1, k0) + DOT4(qb1, k1);
        const float e0 = __expf(s0 * scale);
        const float e1 = __expf(s1 * scale);
        d0 += e0; d1 += e1;
        FMA4(aA0, e0, v0); FMA4(aB0, e0, v1);
        FMA4(aA1, e1, v0); FMA4(aB1, e1, v1);
    }

    __syncthreads();    // all waves done READING the stage
    // partial layout: [wv][row 0..127][3 float4]
    {
        float4* part = smem;
        size_t p = ((size_t)wv * 128 + L) * 3;
        part[p] = aA0; part[p + 1] = aB0; part[p + 2] = make_float4(d0, 0.f, 0.f, 0.f);
        p = ((size_t)wv * 128 + L + 64) * 3;
        part[p] = aA1; part[p + 1] = aB1; part[p + 2] = make_float4(d1, 0.f, 0.f, 0.f);
    }
    __syncthreads();

    if (t < 128) {
        const float4* part = smem;
        float4 rA = make_float4(0.f,0.f,0.f,0.f), rB = rA;
        float rd = 0.f;
        #pragma unroll
        for (int w = 0; w < 4; ++w) {
            const size_t p = ((size_t)w * 128 + t) * 3;
            const float4 a = part[p];
            const float4 b = part[p + 1];
            rA.x += a.x; rA.y += a.y; rA.z += a.z; rA.w += a.w;
            rB.x += b.x; rB.y += b.y; rB.z += b.z; rB.w += b.w;
            rd   += part[p + 2].x;
        }
        const float inv = 1.0f / rd;
        rA.x *= inv; rA.y *= inv; rA.z *= inv; rA.w *= inv;
        rB.x *= inv; rB.y *= inv; rB.z *= inv; rB.w *= inv;
        float4* o = (float4*)hid + ((size_t)bh * 512 + q0 + t) * 2;
        o[0] = rA;
        o[1] = rB;
    }
}

// ---------------------------------------------------------------------------
// Kernel 3: output projection. hid is head-major (B,H,S,8); gather an 8x128
// row-major tile into LDS (transpose), then GEMM with Wo + bo.
// grid 512 x 256: 8 output rows per block.
// ---------------------------------------------------------------------------
__global__ __launch_bounds__(256, 4) void k_out(
    const float* __restrict__ hid, const float* __restrict__ Wo,
    const float* __restrict__ bo, float* __restrict__ out)
{
    __shared__ float hs[8][128];
    const int t = threadIdx.x;
    const int row0 = blockIdx.x * 8;

    // gather: unit u = (row, head), 2 threads per unit (one float4 each)
    {
        const int u    = t >> 1;        // 0..127
        const int half = t & 1;
        const int row  = u >> 4;        // 0..7
        const int h    = u & 15;
        const int g    = row0 + row;
        const int b_   = g >> 9;
        const int s    = g & 511;
        const float4 v = ((const float4*)hid)[(((size_t)b_ * HH + h) * SS + s) * 2 + half];
        *(float4*)&hs[row][h * 8 + half * 4] = v;
    }
    __syncthreads();

    const int cg   = t & 31;
    const int col0 = cg * 4;
    const int rr   = t >> 5;           // 0..7: one row per lane-group

    float4 acc = *(const float4*)&bo[col0];

    #pragma unroll 4
    for (int k4 = 0; k4 < 32; ++k4) {
        const float4 xa = ((const float4*)hs[rr])[k4];
        const float4 w0 = *(const float4*)&Wo[(k4 * 4 + 0) * 128 + col0];
        const float4 w1 = *(const float4*)&Wo[(k4 * 4 + 1) * 128 + col0];
        const float4 w2 = *(const float4*)&Wo[(k4 * 4 + 2) * 128 + col0];
        const float4 w3 = *(const float4*)&Wo[(k4 * 4 + 3) * 128 + col0];
        FMA4(acc, xa.x, w0); FMA4(acc, xa.y, w1);
        FMA4(acc, xa.z, w2); FMA4(acc, xa.w, w3);
    }

    *(float4*)&out[(size_t)(row0 + rr) * 128 + col0] = acc;
}

// ---------------------------------------------------------------------------
extern "C" void kernel_launch(void* const* d_in, const int* in_sizes, int n_in,
                              void* d_out, int out_size, void* d_ws, size_t ws_size,
                              hipStream_t stream)
{
    const float* x     = (const float*)d_in[0];
    const float* Wq    = (const float*)d_in[1];
    const float* bq    = (const float*)d_in[2];
    const float* Wk    = (const float*)d_in[3];
    const float* bk    = (const float*)d_in[4];
    const float* Wv    = (const float*)d_in[5];
    const float* bv    = (const float*)d_in[6];
    const float* Wo    = (const float*)d_in[7];
    const float* bo    = (const float*)d_in[8];
    const float* theta = (const float*)d_in[9];
    float* out = (float*)d_out;

    float* ws  = (float*)d_ws;
    float* qh  = ws;                   // B*H*S*8 = 524288 floats each
    float* kh  = ws + 524288;
    float* vh  = ws + 1048576;
    float* hid = ws + 1572864;         // head-major (B,H,S,8)

    k_qkvq<<<dim3(256, 3), 256, 0, stream>>>(x, Wq, bq, Wk, bk, Wv, bv,
                                             theta, qh, kh, vh);
    k_attn<<<512, 256, 0, stream>>>(qh, kh, vh, hid);
    k_out <<<512, 256, 0, stream>>>(hid, Wo, bo, out);
}

// Round 9
// 46.011 us; speedup vs baseline: 2.0151x; 1.3303x over previous
//
#include <hip/hip_runtime.h>
#include <hip/hip_bf16.h>
#include <math.h>

#define BB 8
#define SS 512
#define EE 128
#define HH 16
#define DKK 8

#define FMA4(ACC, S, W) do { (ACC).x += (S)*(W).x; (ACC).y += (S)*(W).y; \
                             (ACC).z += (S)*(W).z; (ACC).w += (S)*(W).w; } while(0)
#define DOT4(A, B) ((A).x*(B).x + (A).y*(B).y + (A).z*(B).z + (A).w*(B).w)

// ---------------------------------------------------------------------------
// Kernel 1: QKV GEMM + bias + theta + quantum head (R4-proven structure).
// grid (256, 3): blockIdx.x = 16-row x tile, blockIdx.y = matrix (q/k/v).
// block 256 = 4 waves; per-lane tile 2 rows x 4 cols. x tile staged in LDS
// (8KB, broadcast b128 reads); W columns coalesced global float4.
// Quantum head: prefix cosine products; even/odd lane pair swaps one
// 4-product via shfl_xor(1). Output layout (B, H, S, 8).
// ---------------------------------------------------------------------------
__global__ __launch_bounds__(256, 4) void k_qkvq(
    const float* __restrict__ x,
    const float* __restrict__ Wq, const float* __restrict__ bq,
    const float* __restrict__ Wk, const float* __restrict__ bk,
    const float* __restrict__ Wv, const float* __restrict__ bv,
    const float* __restrict__ theta,
    float* __restrict__ qh, float* __restrict__ kh, float* __restrict__ vh)
{
    __shared__ float xs[16][128];
    const int t = threadIdx.x;
    const int m = blockIdx.y;
    const int row0 = blockIdx.x * 16;

    // stage x tile (2048 floats = 512 float4)
    {
        const float4* xv = (const float4*)(x + (size_t)row0 * 128);
        float4* xsv = (float4*)&xs[0][0];
        xsv[t]       = xv[t];
        xsv[t + 256] = xv[t + 256];
    }
    __syncthreads();

    const int cg   = t & 31;
    const int col0 = cg * 4;
    const int rg   = t >> 5;          // 0..7
    const int r0   = rg * 2;

    const float* __restrict__ W  = (m == 0) ? Wq : (m == 1) ? Wk : Wv;
    const float* __restrict__ bb = (m == 0) ? bq : (m == 1) ? bk : bv;
    float* __restrict__ outp     = (m == 0) ? qh : (m == 1) ? kh : vh;

    float4 acc0 = *(const float4*)&bb[col0];
    float4 acc1 = acc0;

    #pragma unroll 4
    for (int k4 = 0; k4 < 32; ++k4) {
        const float4 xa = ((const float4*)xs[r0 + 0])[k4];
        const float4 xb = ((const float4*)xs[r0 + 1])[k4];
        const float4 w0 = *(const float4*)&W[(k4 * 4 + 0) * 128 + col0];
        const float4 w1 = *(const float4*)&W[(k4 * 4 + 1) * 128 + col0];
        const float4 w2 = *(const float4*)&W[(k4 * 4 + 2) * 128 + col0];
        const float4 w3 = *(const float4*)&W[(k4 * 4 + 3) * 128 + col0];
        FMA4(acc0, xa.x, w0); FMA4(acc0, xa.y, w1);
        FMA4(acc0, xa.z, w2); FMA4(acc0, xa.w, w3);
        FMA4(acc1, xb.x, w0); FMA4(acc1, xb.y, w1);
        FMA4(acc1, xb.z, w2); FMA4(acc1, xb.w, w3);
    }

    const float4 th = *(const float4*)&theta[col0];
    const int h    = cg >> 1;
    const int half = cg & 1;          // 0: wires 0-3, 1: wires 4-7

    float4 accs[2] = {acc0, acc1};
    #pragma unroll
    for (int r = 0; r < 2; ++r) {
        float4 c;
        c.x = __cosf(accs[r].x + th.x);
        c.y = __cosf(accs[r].y + th.y);
        c.z = __cosf(accs[r].z + th.z);
        c.w = __cosf(accs[r].w + th.w);
        const float p0 = c.x;
        const float p1 = p0 * c.y;
        const float p2 = p1 * c.z;
        const float p3 = p2 * c.w;
        const float recv = __shfl_xor(p3, 1);
        float4 o;
        if (half == 0) {
            const float s123 = c.y * c.z * c.w;
            o.x = s123 * recv;   // wire 0: c1..c7
            o.y = p1;            // wire 1: c0c1
            o.z = p2;            // wire 2
            o.w = p3;            // wire 3
        } else {
            o.x = recv * p0;     // wire 4: (c0..c3)c4
            o.y = recv * p1;
            o.z = recv * p2;
            o.w = recv * p3;
        }
        const int g  = row0 + r0 + r;
        const int b_ = g >> 9;
        const int s  = g & 511;
        *(float4*)&outp[(((size_t)b_ * HH + h) * SS + s) * DKK + half * 4] = o;
    }
}

// ---------------------------------------------------------------------------
// Kernel 2: attention, R=4 q-rows per lane (amortize ds_read over 4 rows).
// grid 256 = (bh 0..127) x (q-half 0..1 of 256 rows); block 512 = 8 waves.
// Full K+V (32KB) staged in LDS; wave wv covers j-range [wv*64,+64); lane
// owns 4 q rows (L + 64r). q pre-scaled by 1/sqrt(8) -> e = exp(s) direct.
// Single-pass softmax (scores bounded, no max). Partial combine: 8 waves ->
// LDS [4][256][3xf4] (48KB, unioned with the dead K/V stage): waves 0-3
// write, waves 4-7 accumulate, then 256 threads do the 4-way final reduce,
// normalize, and write hid row-major (B,S,E).
// ---------------------------------------------------------------------------
__global__ __launch_bounds__(512, 4) void k_attn(
    const float* __restrict__ qh, const float* __restrict__ kh,
    const float* __restrict__ vh, float* __restrict__ hid)
{
    __shared__ float4 smem[3072];     // 48KB: stage (2048) / partials (3072)
    float4* kk = smem;                // [1024] = 512 rows x 2 float4
    float4* vv = smem + 1024;

    const int t  = threadIdx.x;       // 0..511
    const int L  = t & 63;
    const int wv = t >> 6;            // 0..7
    const int bh = blockIdx.x & 127;
    const int q0 = (blockIdx.x >> 7) * 256;   // 0 or 256

    // stage K/V (2048 float4; 4 per thread, coalesced)
    {
        const float4* kg = (const float4*)kh + (size_t)bh * 1024;
        const float4* vg = (const float4*)vh + (size_t)bh * 1024;
        kk[t]       = kg[t];
        kk[t + 512] = kg[t + 512];
        vv[t]       = vg[t];
        vv[t + 512] = vg[t + 512];
    }

    // this lane's 4 q rows: q0 + L + 64r, pre-scaled by 1/sqrt(8)
    const float scale = 0.35355339059327373f;
    float4 qa[4], qb[4];
    {
        const float4* qg = (const float4*)qh + ((size_t)bh * 512 + q0) * 2;
        #pragma unroll
        for (int r = 0; r < 4; ++r) {
            float4 a = qg[(L + 64 * r) * 2];
            float4 b = qg[(L + 64 * r) * 2 + 1];
            a.x *= scale; a.y *= scale; a.z *= scale; a.w *= scale;
            b.x *= scale; b.y *= scale; b.z *= scale; b.w *= scale;
            qa[r] = a; qb[r] = b;
        }
    }
    __syncthreads();

    float4 aA[4], aB[4];
    float  den[4];
    #pragma unroll
    for (int r = 0; r < 4; ++r) {
        aA[r] = make_float4(0.f, 0.f, 0.f, 0.f);
        aB[r] = make_float4(0.f, 0.f, 0.f, 0.f);
        den[r] = 0.f;
    }

    const float4* kbase = kk + wv * 128;   // this wave's 64 j rows
    const float4* vbase = vv + wv * 128;

    #pragma unroll 4
    for (int j = 0; j < 64; ++j) {
        const float4 k0 = kbase[2 * j];
        const float4 k1 = kbase[2 * j + 1];
        const float4 v0 = vbase[2 * j];
        const float4 v1 = vbase[2 * j + 1];
        #pragma unroll
        for (int r = 0; r < 4; ++r) {
            const float s = DOT4(qa[r], k0) + DOT4(qb[r], k1);
            const float e = __expf(s);
            den[r] += e;
            FMA4(aA[r], e, v0);
            FMA4(aB[r], e, v1);
        }
    }

    __syncthreads();    // all waves done READING the stage

    float4* part = smem;               // [4][256][3] float4
    if (wv < 4) {
        #pragma unroll
        for (int r = 0; r < 4; ++r) {
            const int idx = (wv * 256 + L + 64 * r) * 3;
            part[idx]     = aA[r];
            part[idx + 1] = aB[r];
            part[idx + 2] = make_float4(den[r], 0.f, 0.f, 0.f);
        }
    }
    __syncthreads();
    if (wv >= 4) {
        #pragma unroll
        for (int r = 0; r < 4; ++r) {
            const int idx = ((wv - 4) * 256 + L + 64 * r) * 3;
            float4 pa = part[idx];
            float4 pb = part[idx + 1];
            float4 pd = part[idx + 2];
            pa.x += aA[r].x; pa.y += aA[r].y; pa.z += aA[r].z; pa.w += aA[r].w;
            pb.x += aB[r].x; pb.y += aB[r].y; pb.z += aB[r].z; pb.w += aB[r].w;
            pd.x += den[r];
            part[idx]     = pa;
            part[idx + 1] = pb;
            part[idx + 2] = pd;
        }
    }
    __syncthreads();

    if (t < 256) {
        float4 rA = make_float4(0.f, 0.f, 0.f, 0.f), rB = rA;
        float rd = 0.f;
        #pragma unroll
        for (int w = 0; w < 4; ++w) {
            const int idx = (w * 256 + t) * 3;
            const float4 a = part[idx];
            const float4 b = part[idx + 1];
            rA.x += a.x; rA.y += a.y; rA.z += a.z; rA.w += a.w;
            rB.x += b.x; rB.y += b.y; rB.z += b.z; rB.w += b.w;
            rd   += part[idx + 2].x;
        }
        const float inv = 1.0f / rd;
        rA.x *= inv; rA.y *= inv; rA.z *= inv; rA.w *= inv;
        rB.x *= inv; rB.y *= inv; rB.z *= inv; rB.w *= inv;
        const int b_ = bh >> 4, h = bh & 15;
        float* o = hid + ((size_t)(b_ * 512) + q0 + t) * 128 + h * 8;
        ((float4*)o)[0] = rA;
        ((float4*)o)[1] = rB;
    }
}

// ---------------------------------------------------------------------------
// Kernel 3: output projection hid(4096x128, row-major) @ Wo(128x128) + bo.
// grid 256 x 256: 16 rows/block, LDS stage, per-lane tile 2 rows x 4 cols.
// ---------------------------------------------------------------------------
__global__ __launch_bounds__(256, 4) void k_out(
    const float* __restrict__ hid, const float* __restrict__ Wo,
    const float* __restrict__ bo, float* __restrict__ out)
{
    __shared__ float hs[16][128];
    const int t = threadIdx.x;
    const int row0 = blockIdx.x * 16;

    {
        const float4* hv = (const float4*)(hid + (size_t)row0 * 128);
        float4* hsv = (float4*)&hs[0][0];
        hsv[t]       = hv[t];
        hsv[t + 256] = hv[t + 256];
    }
    __syncthreads();

    const int cg   = t & 31;
    const int col0 = cg * 4;
    const int rg   = t >> 5;
    const int r0   = rg * 2;

    float4 acc0 = *(const float4*)&bo[col0];
    float4 acc1 = acc0;

    #pragma unroll 4
    for (int k4 = 0; k4 < 32; ++k4) {
        const float4 xa = ((const float4*)hs[r0 + 0])[k4];
        const float4 xb = ((const float4*)hs[r0 + 1])[k4];
        const float4 w0 = *(const float4*)&Wo[(k4 * 4 + 0) * 128 + col0];
        const float4 w1 = *(const float4*)&Wo[(k4 * 4 + 1) * 128 + col0];
        const float4 w2 = *(const float4*)&Wo[(k4 * 4 + 2) * 128 + col0];
        const float4 w3 = *(const float4*)&Wo[(k4 * 4 + 3) * 128 + col0];
        FMA4(acc0, xa.x, w0); FMA4(acc0, xa.y, w1);
        FMA4(acc0, xa.z, w2); FMA4(acc0, xa.w, w3);
        FMA4(acc1, xb.x, w0); FMA4(acc1, xb.y, w1);
        FMA4(acc1, xb.z, w2); FMA4(acc1, xb.w, w3);
    }

    *(float4*)&out[(size_t)(row0 + r0 + 0) * 128 + col0] = acc0;
    *(float4*)&out[(size_t)(row0 + r0 + 1) * 128 + col0] = acc1;
}

// ---------------------------------------------------------------------------
extern "C" void kernel_launch(void* const* d_in, const int* in_sizes, int n_in,
                              void* d_out, int out_size, void* d_ws, size_t ws_size,
                              hipStream_t stream)
{
    const float* x     = (const float*)d_in[0];
    const float* Wq    = (const float*)d_in[1];
    const float* bq    = (const float*)d_in[2];
    const float* Wk    = (const float*)d_in[3];
    const float* bk    = (const float*)d_in[4];
    const float* Wv    = (const float*)d_in[5];
    const float* bv    = (const float*)d_in[6];
    const float* Wo    = (const float*)d_in[7];
    const float* bo    = (const float*)d_in[8];
    const float* theta = (const float*)d_in[9];
    float* out = (float*)d_out;

    float* ws  = (float*)d_ws;
    float* qh  = ws;                   // B*H*S*8 = 524288 floats each
    float* kh  = ws + 524288;
    float* vh  = ws + 1048576;
    float* hid = ws + 1572864;         // row-major (B,S,E)

    k_qkvq<<<dim3(256, 3), 256, 0, stream>>>(x, Wq, bq, Wk, bk, Wv, bv,
                                             theta, qh, kh, vh);
    k_attn<<<256, 512, 0, stream>>>(qh, kh, vh, hid);
    k_out <<<256, 256, 0, stream>>>(hid, Wo, bo, out);
}